// Round 7
// baseline (784.898 us; speedup 1.0000x reference)
//
#include <hip/hip_runtime.h>

#define N_PTS 4096
#define NB    8
#define KNN   20
#define FIN   67
#define COUT  64

typedef unsigned long long u64;

// sq = (x*x + y*y) + z*z, all f32, no FMA (matches np op order).
__device__ __forceinline__ float sq_exact(float x, float y, float z) {
#pragma clang fp contract(off)
    float s = (x * x + y * y) + z * z;
    return s;
}

// dist = (sq_i - 2*dot) + sq_j, dot = (x_i*x_j + y_i*y_j) + z_i*z_j, no FMA.
__device__ __forceinline__ float dist_exact(float xi, float yi, float zi, float sqi,
                                            float xj, float yj, float zj) {
#pragma clang fp contract(off)
    float d0 = xi * xj, d1 = yi * yj, d2 = zi * zj;
    float dot = (d0 + d1) + d2;
    float sqj = (xj * xj + yj * yj) + zj * zj;
    float d = (sqi - 2.0f * dot) + sqj;
    return d;
}

__device__ __forceinline__ void insert3(float d, int c,
                                        float& v0, float& v1, float& v2,
                                        int& c0, int& c1, int& c2) {
    if (d < v2) {
        if (d < v1) {
            if (d < v0) { v2 = v1; c2 = c1; v1 = v0; c1 = c0; v0 = d; c0 = c; }
            else        { v2 = v1; c2 = c1; v1 = d;  c1 = c; }
        } else          { v2 = d;  c2 = c; }
    }
}

// One block (64 threads) per output node (b, i). Does EVERYTHING for that node:
//  - lanes 0..2 write output0[b][lane][i] = x_loc (bit-exact f32 copy)
//  - kNN selection over all 4096 candidates (np-exact distance, (dist,idx) order)
//  - gather-sum 20 neighbor feature rows from the [C][N] layout (lane = channel)
//  - dual 67x64 GEMV epilogue + bias + ReLU, write output1[b][lane][i] (f32)
__global__ __launch_bounds__(64) void pcd_all(
    const float* __restrict__ xloc,
    const float* __restrict__ xfeat,
    const float* __restrict__ Wrel,
    const float* __restrict__ brel,
    const float* __restrict__ Wroot,
    float* __restrict__ out) {
    const int lane = threadIdx.x;
    const int row  = blockIdx.x;          // b*4096 + i
    const int b    = row >> 12;
    const int i    = row & (N_PTS - 1);
    const float* xb = xloc + (size_t)b * 3 * N_PTS;

    // Output 0 passthrough: out0[b][c][i] = x_loc[b][c][i] (f32, bit-exact)
    if (lane < 3) {
        out[((size_t)b * 3 + lane) * N_PTS + i] = xb[(size_t)lane * N_PTS + i];
    }

    const float xi  = xb[i];
    const float yi  = xb[N_PTS + i];
    const float zi  = xb[2 * N_PTS + i];
    const float sqi = sq_exact(xi, yi, zi);

    // Per-lane sorted top-3 over its 64 candidates.
    // Candidate c (0..63) -> global j = (c>>2)*256 + lane*4 + (c&3)
    float v0 = 1e30f, v1 = 1e30f, v2 = 1e30f;
    int   c0 = -1,    c1 = -1,    c2 = -1;

    for (int s = 0; s < 16; ++s) {
        int jb = s * 256 + lane * 4;
        float4 fx = *(const float4*)(xb + jb);
        float4 fy = *(const float4*)(xb + N_PTS + jb);
        float4 fz = *(const float4*)(xb + 2 * N_PTS + jb);
#pragma unroll
        for (int q = 0; q < 4; ++q) {
            float xj = (q == 0) ? fx.x : (q == 1) ? fx.y : (q == 2) ? fx.z : fx.w;
            float yj = (q == 0) ? fy.x : (q == 1) ? fy.y : (q == 2) ? fy.z : fy.w;
            float zj = (q == 0) ? fz.x : (q == 1) ? fz.y : (q == 2) ? fz.z : fz.w;
            int j = jb + q;
            float d = (j == i) ? 1e30f : dist_exact(xi, yi, zi, sqi, xj, yj, zj);
            insert3(d, s * 4 + q, v0, v1, v2, c0, c1, c2);
        }
    }

    u64 taken = 0;
    __shared__ int knn[KNN];

    for (int t = 0; t < KNN; ++t) {
        float bv = v0;
        int   bj = (c0 >= 0) ? (((c0 >> 2) << 8) + lane * 4 + (c0 & 3)) : (N_PTS - 1);
#pragma unroll
        for (int m = 1; m < 64; m <<= 1) {
            float ov = __shfl_xor(bv, m);
            int   oj = __shfl_xor(bj, m);
            if (ov < bv || (ov == bv && oj < bj)) { bv = ov; bj = oj; }
        }
        if (lane == 0) knn[t] = bj & (N_PTS - 1);
        int owner = (bj >> 2) & 63;
        if (lane == owner) {
            int cw = (((bj >> 8) << 2) | (bj & 3)) & 63;
            taken |= (1ull << cw);
            v0 = v1; c0 = c1; v1 = v2; c1 = c2; v2 = 1e30f; c2 = -1;
            if (v0 >= 1e30f) {
                // Rare: rebuild top-3 from remaining candidates (identical rounding).
                v0 = v1 = v2 = 1e30f; c0 = c1 = c2 = -1;
                for (int s = 0; s < 16; ++s) {
                    int jb = s * 256 + lane * 4;
                    float4 fx = *(const float4*)(xb + jb);
                    float4 fy = *(const float4*)(xb + N_PTS + jb);
                    float4 fz = *(const float4*)(xb + 2 * N_PTS + jb);
#pragma unroll
                    for (int q = 0; q < 4; ++q) {
                        int cc = s * 4 + q;
                        if ((taken >> cc) & 1ull) continue;
                        int j = jb + q;
                        if (j == i) continue;
                        float xj = (q == 0) ? fx.x : (q == 1) ? fx.y : (q == 2) ? fx.z : fx.w;
                        float yj = (q == 0) ? fy.x : (q == 1) ? fy.y : (q == 2) ? fy.z : fy.w;
                        float zj = (q == 0) ? fz.x : (q == 1) ? fz.y : (q == 2) ? fz.z : fz.w;
                        float d = dist_exact(xi, yi, zi, sqi, xj, yj, zj);
                        insert3(d, cc, v0, v1, v2, c0, c1, c2);
                    }
                }
            }
        }
    }

    __syncthreads();

    // Gather from the native [C][N] layout: lane = feature channel.
    // Per-batch working set (1 MB feat + 48 KB loc) is L2-resident.
    // Neighbor sum in t = ascending-(dist,idx) order, sequential f32 — matches
    // np.sum over the k axis (in-order accumulation for a middle axis).
    __shared__ float aggf[FIN + 1];
    __shared__ float hif[FIN + 1];

    const float* xfb = xfeat + ((size_t)b * 64 + lane) * N_PTS;
    const float* xlb = xb + (size_t)(lane < 3 ? lane : 0) * N_PTS;
    float af = 0.f, al = 0.f;
    for (int t = 0; t < KNN; ++t) {
        int j = knn[t];
        af += xfb[j];
        if (lane < 3) al += xlb[j];
    }
    aggf[3 + lane] = af;
    hif[3 + lane]  = xfb[i];
    if (lane < 3) { aggf[lane] = al; hif[lane] = xlb[i]; }
    __syncthreads();

    // out1[b][lane][i] = relu((agg.Wrel + b_rel) + h_i.Wroot), f32,
    // mirroring np's  einsum + b_rel + einsum  evaluation order.
    float acc_rel = 0.f, acc_root = 0.f;
    for (int f = 0; f < FIN; ++f) {
        acc_rel  += aggf[f] * Wrel[f * COUT + lane];
        acc_root += hif[f]  * Wroot[f * COUT + lane];
    }
    float acc = (acc_rel + brel[lane]) + acc_root;
    acc = fmaxf(acc, 0.0f);
    out[(size_t)NB * 3 * N_PTS + ((((size_t)b << 6) | lane) << 12) + i] = acc;
}

extern "C" void kernel_launch(void* const* d_in, const int* in_sizes, int n_in,
                              void* d_out, int out_size, void* d_ws, size_t ws_size,
                              hipStream_t stream) {
    // Bind inputs by size (element counts, with byte counts also accepted),
    // falling back to the documented setup_inputs() dict order.
    //   x_loc : 98304   x_feat: 2097152   W_rel/W_root: 4288   b_rel: 64   k: 1
    const float* xloc  = nullptr;
    const float* xfeat = nullptr;
    const float* Wrel  = nullptr;
    const float* brel  = nullptr;
    const float* Wroot = nullptr;
    for (int idx = 0; idx < n_in; ++idx) {
        const long long s = in_sizes[idx];
        const float* p = (const float*)d_in[idx];
        if (s == 98304LL || s == 393216LL)          { xloc = p; }
        else if (s == 2097152LL || s == 8388608LL)  { xfeat = p; }
        else if (s == 4288LL || s == 17152LL)       { if (!Wrel) Wrel = p; else Wroot = p; }
        else if (s == 64LL || s == 256LL)           { brel = p; }
    }
    if (!xloc || !xfeat || !Wrel || !brel || !Wroot) {
        xloc  = (const float*)d_in[0];
        xfeat = (const float*)d_in[1];
        Wrel  = (const float*)d_in[2];
        brel  = (const float*)d_in[3];
        Wroot = (const float*)d_in[4];
    }

    pcd_all<<<dim3(NB * N_PTS), dim3(64), 0, stream>>>(
        xloc, xfeat, Wrel, brel, Wroot, (float*)d_out);
}